// Round 12
// baseline (83.739 us; speedup 1.0000x reference)
//
#include <hip/hip_runtime.h>
#include <stdint.h>
#include <type_traits>

// DCN forward: B=4, H=128, W=128, G=8, C=32, K=8
// inputs      [B,H,W,G,C]   fp32
// deformables [B,H,W,G,K,2] fp32
// weights     [B,H,W,G,K]   fp32
// out         [B,H,W,G,C]   fp32
//
// R12 = R11 consolidated:
//  - 1 thread = 1 pixel-group (all 32 ch); block = 16x16 px of one (b,g).
//  - COALESCED staging: linear (cell, unit), 32B/lane contiguous loads,
//    full half8 unit writes (R11's thread-per-cell was 64 trans/inst).
//  - RH=3 halo: 22x22 cells x 80B = 38.7 KB LDS -> 4 blocks/CU.
//  - CUNITS=5 (odd, coprime w/ 8 bank-groups: 5*col mod 8 spans all groups;
//    stride-4 units would alias to {0,4} -> structural 4-way conflict).
//  - interior tiles elide bounds masks; unclamped-index == staging-clamp
//    equivalence (R10 proof); |d|>=3 fallback = exact f32 global gather.

#define Bc 4
#define Hc 128
#define Wc 128
#define Gc 8
#define Kc 8
#define TPX 16
#define RH 3
#define WN 22             // 22x22 cell window
#define NCELL (WN*WN)     // 484
#define CUNITS 5          // half8 units per cell (80 B; 64 B data + pad)

typedef float    float4v __attribute__((ext_vector_type(4)));
typedef _Float16 half8v  __attribute__((ext_vector_type(8)));

__global__ __launch_bounds__(256, 4) void dcn_fwd(
    const float* __restrict__ inp,
    const float* __restrict__ def,
    const float* __restrict__ wts,
    float* __restrict__ out)
{
    const int tid = threadIdx.x;
    const int pw  = tid & 15;
    const int ph  = tid >> 4;

    // grid: wt(8), ht(8), g(8), b(4)
    const int blk = blockIdx.x;
    const int wt = blk & 7;
    const int ht = (blk >> 3) & 7;
    const int g  = (blk >> 6) & 7;
    const int b  = blk >> 9;

    const int h0 = ht * TPX, w0 = wt * TPX;
    const int row0 = h0 - RH, col0 = w0 - RH;   // window origin (may be <0)

    // global plane as float4 units: index = y*8192 + x*64 + u
    const float4v* gp4 = (const float4v*)((const char*)inp
        + ((size_t)b << 24) + ((size_t)g << 7));

    __shared__ half8v tile[NCELL * CUNITS];   // 38720 B

    const int h = h0 + ph;
    const int w = w0 + pw;
    const int pg = ((b * Hc + h) * Wc + w) * Gc + g;

    // issue per-pixel def/wts loads early (independent of LDS)
    const float4v d0 = *(const float4v*)(def + (size_t)pg * 16 + 0);
    const float4v d1 = *(const float4v*)(def + (size_t)pg * 16 + 4);
    const float4v d2 = *(const float4v*)(def + (size_t)pg * 16 + 8);
    const float4v d3 = *(const float4v*)(def + (size_t)pg * 16 + 12);
    const float4v q0 = *(const float4v*)(wts + (size_t)pg * 8 + 0);
    const float4v q1 = *(const float4v*)(wts + (size_t)pg * 8 + 4);

    // ---- stage 22x22 cell window as f16: linear (cell, u2), coalesced ----
    // 484 cells x 4 data units = 1936 half8 writes; lane loads 32B contiguous.
#pragma unroll
    for (int r = 0; r < 8; ++r) {
        const int idx = r * 256 + tid;
        if (idx < NCELL * 4) {
            const int cell = idx >> 2;
            const int u2   = idx & 3;
            const int rr   = (cell * 2979) >> 16;    // exact cell/22, cell<484
            const int cc   = cell - rr * WN;
            const int gr   = min(max(row0 + rr, 0), Hc - 1);
            const int gc   = min(max(col0 + cc, 0), Wc - 1);
            const float4v* src = &gp4[gr * 8192 + gc * 64 + u2 * 2];
            const float4v a = src[0];
            const float4v c = src[1];
            const half8v hv = {(_Float16)a.x, (_Float16)a.y,
                               (_Float16)a.z, (_Float16)a.w,
                               (_Float16)c.x, (_Float16)c.y,
                               (_Float16)c.z, (_Float16)c.w};
            tile[cell * CUNITS + u2] = hv;
        }
    }
    __syncthreads();

    const float dxs[8] = {d0.x, d0.z, d1.x, d1.z, d2.x, d2.z, d3.x, d3.z};
    const float dys[8] = {d0.y, d0.w, d1.y, d1.w, d2.y, d2.w, d3.y, d3.w};
    const float wks[8] = {q0.x, q0.y, q0.z, q0.w, q1.x, q1.y, q1.z, q1.w};

    const float wf = (float)w;
    const float hf = (float)h;

    float acc[32];
#pragma unroll
    for (int i = 0; i < 32; ++i) acc[i] = 0.f;

    auto kloop = [&](auto masked_t) {
        constexpr bool MASKED = decltype(masked_t)::value;
#pragma unroll
        for (int k = 0; k < Kc; ++k) {
            const float dx = dxs[k];
            const float dy = dys[k];
            const float wk = wks[k];

            const float x = dx + wf;
            const float y = dy + hf;

            // truncation toward zero, matching .astype(int32)
            const int fx = (int)x;
            const int fy = (int)y;

            const float wx1 = x - (float)fx;   // exact
            const float wy1 = y - (float)fy;
            const float wx0 = 1.0f - wx1;      // == cxf - x
            const float wy0 = 1.0f - wy1;

            const bool inh = (fabsf(dx) < (float)RH) & (fabsf(dy) < (float)RH);
            if (__builtin_expect(inh, 1)) {
                float ax0 = wx0, ax1 = wx1, ay0 = wy0, ay1 = wy1;
                if constexpr (MASKED) {
                    ax0 = ((uint32_t)fx       < (uint32_t)Wc) ? wx0 : 0.f;
                    ax1 = ((uint32_t)(fx + 1) < (uint32_t)Wc) ? wx1 : 0.f;
                    ay0 = ((uint32_t)fy       < (uint32_t)Hc) ? wy0 : 0.f;
                    ay1 = ((uint32_t)(fy + 1) < (uint32_t)Hc) ? wy1 : 0.f;
                }
                const float ay0k = wk * ay0;
                const float ay1k = wk * ay1;
                const float c00 = ay0k * ax0;
                const float c01 = ay0k * ax1;
                const float c10 = ay1k * ax0;
                const float c11 = ay1k * ax1;

                // unclamped fx,fy valid in-window (|d|<3); staging clamp
                // already equals the reference image clamp.
                const int ib = ((fy - row0) * WN + (fx - col0)) * CUNITS;
#pragma unroll
                for (int u = 0; u < 4; ++u) {
                    const half8v v00 = tile[ib + u];                    // (x  ,y  )
                    const half8v v01 = tile[ib + CUNITS + u];           // (x+1,y  )
                    const half8v v10 = tile[ib + WN*CUNITS + u];        // (x  ,y+1)
                    const half8v v11 = tile[ib + (WN+1)*CUNITS + u];    // (x+1,y+1)
#pragma unroll
                    for (int j = 0; j < 8; ++j) {
                        float s = acc[u * 8 + j];
                        s = fmaf((float)v00[j], c00, s);
                        s = fmaf((float)v01[j], c01, s);
                        s = fmaf((float)v10[j], c10, s);
                        s = fmaf((float)v11[j], c11, s);
                        acc[u * 8 + j] = s;
                    }
                }
            } else {
                // rare: exact f32 global gather with true reference semantics
                const float ax0 = ((uint32_t)fx       < (uint32_t)Wc) ? wx0 : 0.f;
                const float ax1 = ((uint32_t)(fx + 1) < (uint32_t)Wc) ? wx1 : 0.f;
                const float ay0 = ((uint32_t)fy       < (uint32_t)Hc) ? wy0 : 0.f;
                const float ay1 = ((uint32_t)(fy + 1) < (uint32_t)Hc) ? wy1 : 0.f;
                const int xf = min(max(fx,     0), Wc - 1);
                const int xc = min(max(fx + 1, 0), Wc - 1);
                const int yf = min(max(fy,     0), Hc - 1);
                const int yc = min(max(fy + 1, 0), Hc - 1);
                const float ay0k = wk * ay0;
                const float ay1k = wk * ay1;
                const float c00 = ay0k * ax0;
                const float c01 = ay0k * ax1;
                const float c10 = ay1k * ax0;
                const float c11 = ay1k * ax1;
                const float4v* p00 = &gp4[yf * 8192 + xf * 64];
                const float4v* p01 = &gp4[yf * 8192 + xc * 64];
                const float4v* p10 = &gp4[yc * 8192 + xf * 64];
                const float4v* p11 = &gp4[yc * 8192 + xc * 64];
#pragma unroll
                for (int u2 = 0; u2 < 8; ++u2) {
                    const float4v a = p00[u2], bb = p01[u2];
                    const float4v c = p10[u2], dd = p11[u2];
#pragma unroll
                    for (int e = 0; e < 4; ++e) {
                        float s = acc[u2 * 4 + e];
                        s = fmaf(a[e],  c00, s);
                        s = fmaf(bb[e], c01, s);
                        s = fmaf(c[e],  c10, s);
                        s = fmaf(dd[e], c11, s);
                        acc[u2 * 4 + e] = s;
                    }
                }
            }
        }
    };

    // interior tiles: in-halo corners provably in-image -> masks all 1
    const bool interior = ((uint32_t)(wt - 1) <= 5u) & ((uint32_t)(ht - 1) <= 5u);
    if (interior) kloop(std::integral_constant<bool, false>{});
    else          kloop(std::integral_constant<bool, true>{});

    float4v* op = (float4v*)((char*)out + (size_t)pg * 128);
#pragma unroll
    for (int u2 = 0; u2 < 8; ++u2) {
        float4v o = {acc[u2*4], acc[u2*4+1], acc[u2*4+2], acc[u2*4+3]};
        op[u2] = o;
    }
}

extern "C" void kernel_launch(void* const* d_in, const int* in_sizes, int n_in,
                              void* d_out, int out_size, void* d_ws, size_t ws_size,
                              hipStream_t stream) {
    const float* inp = (const float*)d_in[0];
    const float* def = (const float*)d_in[1];
    const float* wts = (const float*)d_in[2];
    float* out = (float*)d_out;

    const int nblocks = Bc * Gc * (Hc / TPX) * (Wc / TPX);  // 2048
    dcn_fwd<<<nblocks, 256, 0, stream>>>(inp, def, wts, out);
}

// Round 13
// 68.009 us; speedup vs baseline: 1.2313x; 1.2313x over previous
//
#include <hip/hip_runtime.h>
#include <stdint.h>
#include <type_traits>

// DCN forward: B=4, H=128, W=128, G=8, C=32, K=8
// inputs      [B,H,W,G,C]   fp32
// deformables [B,H,W,G,K,2] fp32
// weights     [B,H,W,G,K]   fp32
// out         [B,H,W,G,C]   fp32
//
// R13 = R12 with __launch_bounds__(256,3): R12's (256,4) forced VGPR 84->64
// and spilled (WRITE_SIZE 65.5->90.3 MB scratch signature, dur 57->84 us).
// Keeps: 1 thread = 1 pixel-group; coalesced (cell,unit)-linear staging;
// RH=3 halo 22x22 cells = 38.7 KB LDS; CUNITS=5 bank spread; interior
// mask-elision; exact f32 global fallback for |d|>=3.

#define Bc 4
#define Hc 128
#define Wc 128
#define Gc 8
#define Kc 8
#define TPX 16
#define RH 3
#define WN 22             // 22x22 cell window
#define NCELL (WN*WN)     // 484
#define CUNITS 5          // half8 units per cell (80 B; 64 B data + pad)

typedef float    float4v __attribute__((ext_vector_type(4)));
typedef _Float16 half8v  __attribute__((ext_vector_type(8)));

__global__ __launch_bounds__(256, 3) void dcn_fwd(
    const float* __restrict__ inp,
    const float* __restrict__ def,
    const float* __restrict__ wts,
    float* __restrict__ out)
{
    const int tid = threadIdx.x;
    const int pw  = tid & 15;
    const int ph  = tid >> 4;

    // grid: wt(8), ht(8), g(8), b(4)
    const int blk = blockIdx.x;
    const int wt = blk & 7;
    const int ht = (blk >> 3) & 7;
    const int g  = (blk >> 6) & 7;
    const int b  = blk >> 9;

    const int h0 = ht * TPX, w0 = wt * TPX;
    const int row0 = h0 - RH, col0 = w0 - RH;   // window origin (may be <0)

    // global plane as float4 units: index = y*8192 + x*64 + u
    const float4v* gp4 = (const float4v*)((const char*)inp
        + ((size_t)b << 24) + ((size_t)g << 7));

    __shared__ half8v tile[NCELL * CUNITS];   // 38720 B

    const int h = h0 + ph;
    const int w = w0 + pw;
    const int pg = ((b * Hc + h) * Wc + w) * Gc + g;

    // issue per-pixel def/wts loads early (independent of LDS)
    const float4v d0 = *(const float4v*)(def + (size_t)pg * 16 + 0);
    const float4v d1 = *(const float4v*)(def + (size_t)pg * 16 + 4);
    const float4v d2 = *(const float4v*)(def + (size_t)pg * 16 + 8);
    const float4v d3 = *(const float4v*)(def + (size_t)pg * 16 + 12);
    const float4v q0 = *(const float4v*)(wts + (size_t)pg * 8 + 0);
    const float4v q1 = *(const float4v*)(wts + (size_t)pg * 8 + 4);

    // ---- stage 22x22 cell window as f16: linear (cell, u2), coalesced ----
#pragma unroll
    for (int r = 0; r < 8; ++r) {
        const int idx = r * 256 + tid;
        if (idx < NCELL * 4) {
            const int cell = idx >> 2;
            const int u2   = idx & 3;
            const int rr   = (cell * 2979) >> 16;    // exact cell/22, cell<484
            const int cc   = cell - rr * WN;
            const int gr   = min(max(row0 + rr, 0), Hc - 1);
            const int gc   = min(max(col0 + cc, 0), Wc - 1);
            const float4v* src = &gp4[gr * 8192 + gc * 64 + u2 * 2];
            const float4v a = src[0];
            const float4v c = src[1];
            const half8v hv = {(_Float16)a.x, (_Float16)a.y,
                               (_Float16)a.z, (_Float16)a.w,
                               (_Float16)c.x, (_Float16)c.y,
                               (_Float16)c.z, (_Float16)c.w};
            tile[cell * CUNITS + u2] = hv;
        }
    }
    __syncthreads();

    const float dxs[8] = {d0.x, d0.z, d1.x, d1.z, d2.x, d2.z, d3.x, d3.z};
    const float dys[8] = {d0.y, d0.w, d1.y, d1.w, d2.y, d2.w, d3.y, d3.w};
    const float wks[8] = {q0.x, q0.y, q0.z, q0.w, q1.x, q1.y, q1.z, q1.w};

    const float wf = (float)w;
    const float hf = (float)h;

    float acc[32];
#pragma unroll
    for (int i = 0; i < 32; ++i) acc[i] = 0.f;

    auto kloop = [&](auto masked_t) {
        constexpr bool MASKED = decltype(masked_t)::value;
#pragma unroll
        for (int k = 0; k < Kc; ++k) {
            const float dx = dxs[k];
            const float dy = dys[k];
            const float wk = wks[k];

            const float x = dx + wf;
            const float y = dy + hf;

            // truncation toward zero, matching .astype(int32)
            const int fx = (int)x;
            const int fy = (int)y;

            const float wx1 = x - (float)fx;   // exact
            const float wy1 = y - (float)fy;
            const float wx0 = 1.0f - wx1;      // == cxf - x
            const float wy0 = 1.0f - wy1;

            const bool inh = (fabsf(dx) < (float)RH) & (fabsf(dy) < (float)RH);
            if (__builtin_expect(inh, 1)) {
                float ax0 = wx0, ax1 = wx1, ay0 = wy0, ay1 = wy1;
                if constexpr (MASKED) {
                    ax0 = ((uint32_t)fx       < (uint32_t)Wc) ? wx0 : 0.f;
                    ax1 = ((uint32_t)(fx + 1) < (uint32_t)Wc) ? wx1 : 0.f;
                    ay0 = ((uint32_t)fy       < (uint32_t)Hc) ? wy0 : 0.f;
                    ay1 = ((uint32_t)(fy + 1) < (uint32_t)Hc) ? wy1 : 0.f;
                }
                const float ay0k = wk * ay0;
                const float ay1k = wk * ay1;
                const float c00 = ay0k * ax0;
                const float c01 = ay0k * ax1;
                const float c10 = ay1k * ax0;
                const float c11 = ay1k * ax1;

                // unclamped fx,fy valid in-window (|d|<3); staging clamp
                // already equals the reference image clamp.
                const int ib = ((fy - row0) * WN + (fx - col0)) * CUNITS;
#pragma unroll
                for (int u = 0; u < 4; ++u) {
                    const half8v v00 = tile[ib + u];                    // (x  ,y  )
                    const half8v v01 = tile[ib + CUNITS + u];           // (x+1,y  )
                    const half8v v10 = tile[ib + WN*CUNITS + u];        // (x  ,y+1)
                    const half8v v11 = tile[ib + (WN+1)*CUNITS + u];    // (x+1,y+1)
#pragma unroll
                    for (int j = 0; j < 8; ++j) {
                        float s = acc[u * 8 + j];
                        s = fmaf((float)v00[j], c00, s);
                        s = fmaf((float)v01[j], c01, s);
                        s = fmaf((float)v10[j], c10, s);
                        s = fmaf((float)v11[j], c11, s);
                        acc[u * 8 + j] = s;
                    }
                }
            } else {
                // rare: exact f32 global gather with true reference semantics
                const float ax0 = ((uint32_t)fx       < (uint32_t)Wc) ? wx0 : 0.f;
                const float ax1 = ((uint32_t)(fx + 1) < (uint32_t)Wc) ? wx1 : 0.f;
                const float ay0 = ((uint32_t)fy       < (uint32_t)Hc) ? wy0 : 0.f;
                const float ay1 = ((uint32_t)(fy + 1) < (uint32_t)Hc) ? wy1 : 0.f;
                const int xf = min(max(fx,     0), Wc - 1);
                const int xc = min(max(fx + 1, 0), Wc - 1);
                const int yf = min(max(fy,     0), Hc - 1);
                const int yc = min(max(fy + 1, 0), Hc - 1);
                const float ay0k = wk * ay0;
                const float ay1k = wk * ay1;
                const float c00 = ay0k * ax0;
                const float c01 = ay0k * ax1;
                const float c10 = ay1k * ax0;
                const float c11 = ay1k * ax1;
                const float4v* p00 = &gp4[yf * 8192 + xf * 64];
                const float4v* p01 = &gp4[yf * 8192 + xc * 64];
                const float4v* p10 = &gp4[yc * 8192 + xf * 64];
                const float4v* p11 = &gp4[yc * 8192 + xc * 64];
#pragma unroll
                for (int u2 = 0; u2 < 8; ++u2) {
                    const float4v a = p00[u2], bb = p01[u2];
                    const float4v c = p10[u2], dd = p11[u2];
#pragma unroll
                    for (int e = 0; e < 4; ++e) {
                        float s = acc[u2 * 4 + e];
                        s = fmaf(a[e],  c00, s);
                        s = fmaf(bb[e], c01, s);
                        s = fmaf(c[e],  c10, s);
                        s = fmaf(dd[e], c11, s);
                        acc[u2 * 4 + e] = s;
                    }
                }
            }
        }
    };

    // interior tiles: in-halo corners provably in-image -> masks all 1
    const bool interior = ((uint32_t)(wt - 1) <= 5u) & ((uint32_t)(ht - 1) <= 5u);
    if (interior) kloop(std::integral_constant<bool, false>{});
    else          kloop(std::integral_constant<bool, true>{});

    float4v* op = (float4v*)((char*)out + (size_t)pg * 128);
#pragma unroll
    for (int u2 = 0; u2 < 8; ++u2) {
        float4v o = {acc[u2*4], acc[u2*4+1], acc[u2*4+2], acc[u2*4+3]};
        op[u2] = o;
    }
}

extern "C" void kernel_launch(void* const* d_in, const int* in_sizes, int n_in,
                              void* d_out, int out_size, void* d_ws, size_t ws_size,
                              hipStream_t stream) {
    const float* inp = (const float*)d_in[0];
    const float* def = (const float*)d_in[1];
    const float* wts = (const float*)d_in[2];
    float* out = (float*)d_out;

    const int nblocks = Bc * Gc * (Hc / TPX) * (Wc / TPX);  // 2048
    dcn_fwd<<<nblocks, 256, 0, stream>>>(inp, def, wts, out);
}

// Round 14
// 54.184 us; speedup vs baseline: 1.5455x; 1.2552x over previous
//
#include <hip/hip_runtime.h>
#include <stdint.h>
#include <type_traits>

// DCN forward: B=4, H=128, W=128, G=8, C=32, K=8
// inputs      [B,H,W,G,C]   fp32
// deformables [B,H,W,G,K,2] fp32
// weights     [B,H,W,G,K]   fp32
// out         [B,H,W,G,C]   fp32
//
// R14 = R11 math (RH=4: fallback P~1e-4, no wave divergence; R13's RH=3 cost
// ~2.8 divergent events/wave = +11 us) + R13's coalesced staging + 2 lanes/px:
//  - block 512 thr = 16x16 px tile, 2 lanes/pixel (16 ch each) -> 8 waves/blk,
//    46 KB LDS -> 3 blocks/CU -> 24 resident waves (75%) vs R11's ~2 blocks.
//    FMA/LDS totals are mapping-invariant; coord math still amortized x32.
//  - RH=4 halo: 24x24 cells x 80 B (CUNITS=5, odd: +5 mod 8 bank-group
//    cycling) = 46080 B.
//  - coalesced (cell,unit)-linear staging: 32B/lane contiguous loads.
//  - interior tiles (wt,ht in [1,6]) elide bounds masks; unclamped-index ==
//    staging-clamp equivalence (R10 proof); |d|>=4 fallback = exact f32 gather.

#define Bc 4
#define Hc 128
#define Wc 128
#define Gc 8
#define Kc 8
#define TPX 16
#define RH 4
#define WN 24             // 24x24 cell window
#define NCELL (WN*WN)     // 576
#define CUNITS 5          // half8 units per cell (80 B; 64 B data + pad)

typedef float    float4v __attribute__((ext_vector_type(4)));
typedef _Float16 half8v  __attribute__((ext_vector_type(8)));

__global__ __launch_bounds__(512, 4) void dcn_fwd(
    const float* __restrict__ inp,
    const float* __restrict__ def,
    const float* __restrict__ wts,
    float* __restrict__ out)
{
    const int tid = threadIdx.x;
    const int j   = tid & 1;       // lane half: channels j*16 .. j*16+15
    const int px  = tid >> 1;      // 0..255 pixel in tile
    const int pw  = px & 15;
    const int ph  = px >> 4;

    // grid: wt(8), ht(8), g(8), b(4)
    const int blk = blockIdx.x;
    const int wt = blk & 7;
    const int ht = (blk >> 3) & 7;
    const int g  = (blk >> 6) & 7;
    const int b  = blk >> 9;

    const int h0 = ht * TPX, w0 = wt * TPX;
    const int row0 = h0 - RH, col0 = w0 - RH;   // window origin (may be <0)

    // global plane as float4 units: index = y*8192 + x*64 + u
    const float4v* gp4 = (const float4v*)((const char*)inp
        + ((size_t)b << 24) + ((size_t)g << 7));

    __shared__ half8v tile[NCELL * CUNITS];   // 46080 B

    const int h = h0 + ph;
    const int w = w0 + pw;
    const int pg = ((b * Hc + h) * Wc + w) * Gc + g;

    // per-pixel def/wts (both lanes of a pixel load the same; L1 merges)
    const float4v d0 = *(const float4v*)(def + (size_t)pg * 16 + 0);
    const float4v d1 = *(const float4v*)(def + (size_t)pg * 16 + 4);
    const float4v d2 = *(const float4v*)(def + (size_t)pg * 16 + 8);
    const float4v d3 = *(const float4v*)(def + (size_t)pg * 16 + 12);
    const float4v q0 = *(const float4v*)(wts + (size_t)pg * 8 + 0);
    const float4v q1 = *(const float4v*)(wts + (size_t)pg * 8 + 4);

    // ---- stage 24x24 cell window as f16: linear (cell, u2), coalesced ----
    // 576 cells x 4 data units = 2304 half8 writes; lane loads 32B contiguous.
#pragma unroll
    for (int r = 0; r < 5; ++r) {
        const int idx = r * 512 + tid;
        if (idx < NCELL * 4) {
            const int cell = idx >> 2;
            const int u2   = idx & 3;
            const int rr   = (cell * 2731) >> 16;    // exact cell/24, cell<576
            const int cc   = cell - rr * WN;
            const int gr   = min(max(row0 + rr, 0), Hc - 1);
            const int gc   = min(max(col0 + cc, 0), Wc - 1);
            const float4v* src = &gp4[gr * 8192 + gc * 64 + u2 * 2];
            const float4v a = src[0];
            const float4v c = src[1];
            const half8v hv = {(_Float16)a.x, (_Float16)a.y,
                               (_Float16)a.z, (_Float16)a.w,
                               (_Float16)c.x, (_Float16)c.y,
                               (_Float16)c.z, (_Float16)c.w};
            tile[cell * CUNITS + u2] = hv;
        }
    }
    __syncthreads();

    const float dxs[8] = {d0.x, d0.z, d1.x, d1.z, d2.x, d2.z, d3.x, d3.z};
    const float dys[8] = {d0.y, d0.w, d1.y, d1.w, d2.y, d2.w, d3.y, d3.w};
    const float wks[8] = {q0.x, q0.y, q0.z, q0.w, q1.x, q1.y, q1.z, q1.w};

    const float wf = (float)w;
    const float hf = (float)h;
    const int ju = j * 2;          // first half8 unit owned by this lane

    float acc[16];
#pragma unroll
    for (int i = 0; i < 16; ++i) acc[i] = 0.f;

    auto kloop = [&](auto masked_t) {
        constexpr bool MASKED = decltype(masked_t)::value;
#pragma unroll
        for (int k = 0; k < Kc; ++k) {
            const float dx = dxs[k];
            const float dy = dys[k];
            const float wk = wks[k];

            const float x = dx + wf;
            const float y = dy + hf;

            // truncation toward zero, matching .astype(int32)
            const int fx = (int)x;
            const int fy = (int)y;

            const float wx1 = x - (float)fx;   // exact
            const float wy1 = y - (float)fy;
            const float wx0 = 1.0f - wx1;      // == cxf - x
            const float wy0 = 1.0f - wy1;

            const bool inh = (fabsf(dx) < 4.0f) & (fabsf(dy) < 4.0f);
            if (__builtin_expect(inh, 1)) {
                float ax0 = wx0, ax1 = wx1, ay0 = wy0, ay1 = wy1;
                if constexpr (MASKED) {
                    ax0 = ((uint32_t)fx       < (uint32_t)Wc) ? wx0 : 0.f;
                    ax1 = ((uint32_t)(fx + 1) < (uint32_t)Wc) ? wx1 : 0.f;
                    ay0 = ((uint32_t)fy       < (uint32_t)Hc) ? wy0 : 0.f;
                    ay1 = ((uint32_t)(fy + 1) < (uint32_t)Hc) ? wy1 : 0.f;
                }
                const float ay0k = wk * ay0;
                const float ay1k = wk * ay1;
                const float c00 = ay0k * ax0;
                const float c01 = ay0k * ax1;
                const float c10 = ay1k * ax0;
                const float c11 = ay1k * ax1;

                // unclamped fx,fy valid in-window (|d|<4); staging clamp
                // already equals the reference image clamp.
                const int ib = ((fy - row0) * WN + (fx - col0)) * CUNITS + ju;
#pragma unroll
                for (int u = 0; u < 2; ++u) {
                    const half8v v00 = tile[ib + u];                    // (x  ,y  )
                    const half8v v01 = tile[ib + CUNITS + u];           // (x+1,y  )
                    const half8v v10 = tile[ib + WN*CUNITS + u];        // (x  ,y+1)
                    const half8v v11 = tile[ib + (WN+1)*CUNITS + u];    // (x+1,y+1)
#pragma unroll
                    for (int l = 0; l < 8; ++l) {
                        float s = acc[u * 8 + l];
                        s = fmaf((float)v00[l], c00, s);
                        s = fmaf((float)v01[l], c01, s);
                        s = fmaf((float)v10[l], c10, s);
                        s = fmaf((float)v11[l], c11, s);
                        acc[u * 8 + l] = s;
                    }
                }
            } else {
                // rare (P~1e-4): exact f32 global gather, true reference clamps
                const float ax0 = ((uint32_t)fx       < (uint32_t)Wc) ? wx0 : 0.f;
                const float ax1 = ((uint32_t)(fx + 1) < (uint32_t)Wc) ? wx1 : 0.f;
                const float ay0 = ((uint32_t)fy       < (uint32_t)Hc) ? wy0 : 0.f;
                const float ay1 = ((uint32_t)(fy + 1) < (uint32_t)Hc) ? wy1 : 0.f;
                const int xf = min(max(fx,     0), Wc - 1);
                const int xc = min(max(fx + 1, 0), Wc - 1);
                const int yf = min(max(fy,     0), Hc - 1);
                const int yc = min(max(fy + 1, 0), Hc - 1);
                const float ay0k = wk * ay0;
                const float ay1k = wk * ay1;
                const float c00 = ay0k * ax0;
                const float c01 = ay0k * ax1;
                const float c10 = ay1k * ax0;
                const float c11 = ay1k * ax1;
                const float4v* p00 = &gp4[yf * 8192 + xf * 64 + 4 * j];
                const float4v* p01 = &gp4[yf * 8192 + xc * 64 + 4 * j];
                const float4v* p10 = &gp4[yc * 8192 + xf * 64 + 4 * j];
                const float4v* p11 = &gp4[yc * 8192 + xc * 64 + 4 * j];
#pragma unroll
                for (int u4 = 0; u4 < 4; ++u4) {
                    const float4v a = p00[u4], bb = p01[u4];
                    const float4v c = p10[u4], dd = p11[u4];
#pragma unroll
                    for (int e = 0; e < 4; ++e) {
                        float s = acc[u4 * 4 + e];
                        s = fmaf(a[e],  c00, s);
                        s = fmaf(bb[e], c01, s);
                        s = fmaf(c[e],  c10, s);
                        s = fmaf(dd[e], c11, s);
                        acc[u4 * 4 + e] = s;
                    }
                }
            }
        }
    };

    // interior tiles: in-halo corners provably in-image -> masks all 1
    const bool interior = ((uint32_t)(wt - 1) <= 5u) & ((uint32_t)(ht - 1) <= 5u);
    if (interior) kloop(std::integral_constant<bool, false>{});
    else          kloop(std::integral_constant<bool, true>{});

    // channels j*16 .. j*16+15 = float4 units 4j..4j+3 (64 B contiguous)
    float4v* op = (float4v*)((char*)out + (size_t)pg * 128) + 4 * j;
#pragma unroll
    for (int u4 = 0; u4 < 4; ++u4) {
        float4v o = {acc[u4*4], acc[u4*4+1], acc[u4*4+2], acc[u4*4+3]};
        op[u4] = o;
    }
}

extern "C" void kernel_launch(void* const* d_in, const int* in_sizes, int n_in,
                              void* d_out, int out_size, void* d_ws, size_t ws_size,
                              hipStream_t stream) {
    const float* inp = (const float*)d_in[0];
    const float* def = (const float*)d_in[1];
    const float* wts = (const float*)d_in[2];
    float* out = (float*)d_out;

    const int nblocks = Bc * Gc * (Hc / TPX) * (Wc / TPX);  // 2048
    dcn_fwd<<<nblocks, 512, 0, stream>>>(inp, def, wts, out);
}

// Round 15
// 43.489 us; speedup vs baseline: 1.9255x; 1.2459x over previous
//
#include <hip/hip_runtime.h>
#include <stdint.h>
#include <type_traits>

// DCN forward: B=4, H=128, W=128, G=8, C=32, K=8
// inputs      [B,H,W,G,C]   fp32
// deformables [B,H,W,G,K,2] fp32
// weights     [B,H,W,G,K]   fp32
// out         [B,H,W,G,C]   fp32
//
// R15 = R14 with: (1) forced v_fma_mix_f32 (inline asm, f16 src via op_sel,
// exact f32 fma -> 1 VALU inst/channel; R14 showed ~2x inst count = cvt not
// folded); (2) 4 lanes/pixel -> each ds_read_b128 phase = 2 pixels -> at most
// 2-way bank conflict (free, m136); 1 read/corner at imm offsets 0/80/1920/
// 2000 B off one addr reg; (3) 8x16 px tile -> 16x24-cell halo = 30.7 KB LDS
// -> 5 blocks/CU. Keeps RH=4 (no divergence), CUNITS=5, coalesced staging,
// interior mask-elision, unclamped-index == staging-clamp equivalence, exact
// f32 global fallback.

#define Bc 4
#define Hc 128
#define Wc 128
#define Gc 8
#define Kc 8
#define TH 8
#define TW 16
#define RH 4
#define WR 16             // window rows = TH + 2*RH
#define WN 24             // window cols = TW + 2*RH
#define NCELL (WR*WN)     // 384
#define CUNITS 5          // 16B units per cell (80 B; 64 B data + 16 pad)

typedef float    float4v __attribute__((ext_vector_type(4)));
typedef _Float16 half8v  __attribute__((ext_vector_type(8)));
typedef uint32_t uint4v  __attribute__((ext_vector_type(4)));

union PkU { half8v h; uint4v u; };

// acc += (f16 lo/hi of PK) * C   -- exact f32 fma, f16 converted exactly
#define FMA_MIX_LO(ACC, PK, C) \
    asm("v_fma_mix_f32 %0, %1, %2, %0 op_sel:[0,0,0] op_sel_hi:[1,0,0]" \
        : "+v"(ACC) : "v"(PK), "v"(C))
#define FMA_MIX_HI(ACC, PK, C) \
    asm("v_fma_mix_f32 %0, %1, %2, %0 op_sel:[1,0,0] op_sel_hi:[1,0,0]" \
        : "+v"(ACC) : "v"(PK), "v"(C))

__global__ __launch_bounds__(512, 4) void dcn_fwd(
    const float* __restrict__ inp,
    const float* __restrict__ def,
    const float* __restrict__ wts,
    float* __restrict__ out)
{
    const int tid = threadIdx.x;
    const int j   = tid & 3;       // lane owns channels 8j..8j+7 (one 16B unit)
    const int px  = tid >> 2;      // 0..127 pixel in tile
    const int pw  = px & 15;
    const int ph  = px >> 4;

    // grid: wt(8), ht(16), g(8), b(4)
    const int blk = blockIdx.x;
    const int wt = blk & 7;
    const int ht = (blk >> 3) & 15;
    const int g  = (blk >> 7) & 7;
    const int b  = blk >> 10;

    const int h0 = ht * TH, w0 = wt * TW;
    const int row0 = h0 - RH, col0 = w0 - RH;   // window origin (may be <0)

    // global plane as float4 units: index = y*8192 + x*64 + u
    const float4v* gp4 = (const float4v*)((const char*)inp
        + ((size_t)b << 24) + ((size_t)g << 7));

    __shared__ uint4v tile[NCELL * CUNITS];   // 30720 B

    const int h = h0 + ph;
    const int w = w0 + pw;
    const int pg = ((b * Hc + h) * Wc + w) * Gc + g;

    // per-pixel def/wts (4 lanes load same addr; coalescer merges)
    const float4v d0 = *(const float4v*)(def + (size_t)pg * 16 + 0);
    const float4v d1 = *(const float4v*)(def + (size_t)pg * 16 + 4);
    const float4v d2 = *(const float4v*)(def + (size_t)pg * 16 + 8);
    const float4v d3 = *(const float4v*)(def + (size_t)pg * 16 + 12);
    const float4v q0 = *(const float4v*)(wts + (size_t)pg * 8 + 0);
    const float4v q1 = *(const float4v*)(wts + (size_t)pg * 8 + 4);

    // ---- stage 16x24 cell window as f16 (RTE): linear (cell,u2), coalesced ----
    // 384 cells x 4 units = 1536 writes; 3 exact rounds of 512.
#pragma unroll
    for (int r = 0; r < 3; ++r) {
        const int idx  = r * 512 + tid;
        const int cell = idx >> 2;
        const int u2   = idx & 3;
        const int rr   = (cell * 2731) >> 16;    // exact cell/24 for cell<576
        const int cc   = cell - rr * WN;
        const int gr   = min(max(row0 + rr, 0), Hc - 1);
        const int gc   = min(max(col0 + cc, 0), Wc - 1);
        const float4v* src = &gp4[gr * 8192 + gc * 64 + u2 * 2];
        const float4v a = src[0];
        const float4v c = src[1];
        PkU p;
        p.h = (half8v){(_Float16)a.x, (_Float16)a.y, (_Float16)a.z, (_Float16)a.w,
                       (_Float16)c.x, (_Float16)c.y, (_Float16)c.z, (_Float16)c.w};
        tile[cell * CUNITS + u2] = p.u;
    }
    __syncthreads();

    const float dxs[8] = {d0.x, d0.z, d1.x, d1.z, d2.x, d2.z, d3.x, d3.z};
    const float dys[8] = {d0.y, d0.w, d1.y, d1.w, d2.y, d2.w, d3.y, d3.w};
    const float wks[8] = {q0.x, q0.y, q0.z, q0.w, q1.x, q1.y, q1.z, q1.w};

    const float wf = (float)w;
    const float hf = (float)h;

    float acc[8];
#pragma unroll
    for (int i = 0; i < 8; ++i) acc[i] = 0.f;

    auto kloop = [&](auto masked_t) {
        constexpr bool MASKED = decltype(masked_t)::value;
#pragma unroll
        for (int k = 0; k < Kc; ++k) {
            const float dx = dxs[k];
            const float dy = dys[k];
            const float wk = wks[k];

            const float x = dx + wf;
            const float y = dy + hf;

            // truncation toward zero, matching .astype(int32)
            const int fx = (int)x;
            const int fy = (int)y;

            const float wx1 = x - (float)fx;   // exact
            const float wy1 = y - (float)fy;
            const float wx0 = 1.0f - wx1;      // == cxf - x
            const float wy0 = 1.0f - wy1;

            const bool inh = (fabsf(dx) < 4.0f) & (fabsf(dy) < 4.0f);
            if (__builtin_expect(inh, 1)) {
                float ax0 = wx0, ax1 = wx1, ay0 = wy0, ay1 = wy1;
                if constexpr (MASKED) {
                    ax0 = ((uint32_t)fx       < (uint32_t)Wc) ? wx0 : 0.f;
                    ax1 = ((uint32_t)(fx + 1) < (uint32_t)Wc) ? wx1 : 0.f;
                    ay0 = ((uint32_t)fy       < (uint32_t)Hc) ? wy0 : 0.f;
                    ay1 = ((uint32_t)(fy + 1) < (uint32_t)Hc) ? wy1 : 0.f;
                }
                const float ay0k = wk * ay0;
                const float ay1k = wk * ay1;
                const float c00 = ay0k * ax0;
                const float c01 = ay0k * ax1;
                const float c10 = ay1k * ax0;
                const float c11 = ay1k * ax1;

                // unclamped fx,fy valid in-window (|d|<4); staging clamp
                // already equals the reference image clamp.
                const int iu = ((fy - row0) * WN + (fx - col0)) * CUNITS + j;
                const uint4v v00 = tile[iu];                      // (x  ,y  )
                const uint4v v01 = tile[iu + CUNITS];             // (x+1,y  )
                const uint4v v10 = tile[iu + WN * CUNITS];        // (x  ,y+1)
                const uint4v v11 = tile[iu + (WN + 1) * CUNITS];  // (x+1,y+1)

                FMA_MIX_LO(acc[0], v00.x, c00); FMA_MIX_HI(acc[1], v00.x, c00);
                FMA_MIX_LO(acc[2], v00.y, c00); FMA_MIX_HI(acc[3], v00.y, c00);
                FMA_MIX_LO(acc[4], v00.z, c00); FMA_MIX_HI(acc[5], v00.z, c00);
                FMA_MIX_LO(acc[6], v00.w, c00); FMA_MIX_HI(acc[7], v00.w, c00);

                FMA_MIX_LO(acc[0], v01.x, c01); FMA_MIX_HI(acc[1], v01.x, c01);
                FMA_MIX_LO(acc[2], v01.y, c01); FMA_MIX_HI(acc[3], v01.y, c01);
                FMA_MIX_LO(acc[4], v01.z, c01); FMA_MIX_HI(acc[5], v01.z, c01);
                FMA_MIX_LO(acc[6], v01.w, c01); FMA_MIX_HI(acc[7], v01.w, c01);

                FMA_MIX_LO(acc[0], v10.x, c10); FMA_MIX_HI(acc[1], v10.x, c10);
                FMA_MIX_LO(acc[2], v10.y, c10); FMA_MIX_HI(acc[3], v10.y, c10);
                FMA_MIX_LO(acc[4], v10.z, c10); FMA_MIX_HI(acc[5], v10.z, c10);
                FMA_MIX_LO(acc[6], v10.w, c10); FMA_MIX_HI(acc[7], v10.w, c10);

                FMA_MIX_LO(acc[0], v11.x, c11); FMA_MIX_HI(acc[1], v11.x, c11);
                FMA_MIX_LO(acc[2], v11.y, c11); FMA_MIX_HI(acc[3], v11.y, c11);
                FMA_MIX_LO(acc[4], v11.z, c11); FMA_MIX_HI(acc[5], v11.z, c11);
                FMA_MIX_LO(acc[6], v11.w, c11); FMA_MIX_HI(acc[7], v11.w, c11);
            } else {
                // rare (P~1e-4): exact f32 global gather, true reference clamps
                const float ax0 = ((uint32_t)fx       < (uint32_t)Wc) ? wx0 : 0.f;
                const float ax1 = ((uint32_t)(fx + 1) < (uint32_t)Wc) ? wx1 : 0.f;
                const float ay0 = ((uint32_t)fy       < (uint32_t)Hc) ? wy0 : 0.f;
                const float ay1 = ((uint32_t)(fy + 1) < (uint32_t)Hc) ? wy1 : 0.f;
                const int xf = min(max(fx,     0), Wc - 1);
                const int xc = min(max(fx + 1, 0), Wc - 1);
                const int yf = min(max(fy,     0), Hc - 1);
                const int yc = min(max(fy + 1, 0), Hc - 1);
                const float ay0k = wk * ay0;
                const float ay1k = wk * ay1;
                const float c00 = ay0k * ax0;
                const float c01 = ay0k * ax1;
                const float c10 = ay1k * ax0;
                const float c11 = ay1k * ax1;
                const float4v* p00 = &gp4[yf * 8192 + xf * 64 + 2 * j];
                const float4v* p01 = &gp4[yf * 8192 + xc * 64 + 2 * j];
                const float4v* p10 = &gp4[yc * 8192 + xf * 64 + 2 * j];
                const float4v* p11 = &gp4[yc * 8192 + xc * 64 + 2 * j];
#pragma unroll
                for (int u2 = 0; u2 < 2; ++u2) {
                    const float4v a = p00[u2], bb = p01[u2];
                    const float4v c = p10[u2], dd = p11[u2];
#pragma unroll
                    for (int e = 0; e < 4; ++e) {
                        float s = acc[u2 * 4 + e];
                        s = fmaf(a[e],  c00, s);
                        s = fmaf(bb[e], c01, s);
                        s = fmaf(c[e],  c10, s);
                        s = fmaf(dd[e], c11, s);
                        acc[u2 * 4 + e] = s;
                    }
                }
            }
        }
    };

    // interior tiles: in-halo corners provably in-image -> masks all 1
    const bool interior = ((uint32_t)(wt - 1) <= 5u) & ((uint32_t)(ht - 1) <= 13u);
    if (interior) kloop(std::integral_constant<bool, false>{});
    else          kloop(std::integral_constant<bool, true>{});

    // channels 8j..8j+7 = float4 units 2j, 2j+1 (32 B contiguous)
    float4v* op = (float4v*)((char*)out + (size_t)pg * 128) + 2 * j;
    float4v o0 = {acc[0], acc[1], acc[2], acc[3]};
    float4v o1 = {acc[4], acc[5], acc[6], acc[7]};
    op[0] = o0;
    op[1] = o1;
}

extern "C" void kernel_launch(void* const* d_in, const int* in_sizes, int n_in,
                              void* d_out, int out_size, void* d_ws, size_t ws_size,
                              hipStream_t stream) {
    const float* inp = (const float*)d_in[0];
    const float* def = (const float*)d_in[1];
    const float* wts = (const float*)d_in[2];
    float* out = (float*)d_out;

    const int nblocks = Bc * Gc * (Hc / TH) * (Wc / TW);  // 4096
    dcn_fwd<<<nblocks, 512, 0, stream>>>(inp, def, wts, out);
}